// Round 1
// baseline (1528.258 us; speedup 1.0000x reference)
//
#include <hip/hip_runtime.h>
#include <math.h>

namespace {

constexpr int D = 300;
constexpr int H = 512;
constexpr int LP = 4096;
constexpr int LH = 4096;
constexpr int LT = LP + LH;  // 8192

constexpr int BM = 64, BN = 64, BK = 16;

// ---------------- workspace layout (float offsets) ----------------
constexpr size_t WS_PEHE = 0;                                   // [8192][300]
constexpr size_t WS_T1   = WS_PEHE + (size_t)LT * D;            // [8192][512]
constexpr size_t WS_FPFH = WS_T1 + (size_t)LT * H;              // [8192][512]
constexpr size_t WS_SH   = WS_FPFH + (size_t)LT * H;            // [512]
constexpr size_t WS_CF   = WS_SH + H;                           // [512]
constexpr size_t WS_EIK  = WS_CF + H;                           // [4096]
constexpr size_t WS_EKJ  = WS_EIK + LP;                         // [4096]
constexpr size_t WS_GH   = WS_EKJ + LH;                         // [512*300]
constexpr size_t WS_GP   = WS_GH + (size_t)H * D;               // [512*300]
constexpr size_t WS_PART = WS_GP + (size_t)H * D;               // [8][512*300] split-K partials
constexpr size_t WS_PART2= WS_PART + (size_t)8 * H * D;         // [16*512] colsum partials
constexpr size_t WS_G1V  = WS_PART2 + (size_t)16 * H;           // [512]
constexpr size_t WS_G2V  = WS_G1V + H;                          // [512]

// ---------------- output layout (float offsets) ----------------
constexpr size_t OUT_E     = 0;
constexpr size_t OUT_BETA  = (size_t)LP * LH;
constexpr size_t OUT_ALPHA = OUT_BETA + (size_t)LP * D;
constexpr size_t OUT_V1    = OUT_ALPHA + (size_t)LH * D;
constexpr size_t OUT_V2    = OUT_V1 + H;
constexpr size_t OUT_Y     = OUT_V2 + H;

// ---------------- kernels ----------------

__global__ __launch_bounds__(128)
void gather_kernel(const int* __restrict__ p_idx, const int* __restrict__ h_idx,
                   const float* __restrict__ emb, float* __restrict__ dst) {
  const int row = blockIdx.x;  // 0..8191
  const int r = row < LP ? row : row - LP;
  const int src = row < LP ? p_idx[r] : h_idx[r];
  const float4* s = (const float4*)(emb + (size_t)src * D);
  float4* d = (float4*)(dst + (size_t)row * D);
  const int c = threadIdx.x;
  if (c < D / 4) d[c] = s[c];  // 75 float4 per row
}

// OUT[m,n] = relu( sum_k X[m,k] * W[n,k] + bias[n] ), X = concat(X1[K1], X2[K2]) along k
__global__ __launch_bounds__(256)
void linear_relu_kernel(const float* __restrict__ X1, int K1,
                        const float* __restrict__ X2, int K2,
                        const float* __restrict__ W, const float* __restrict__ bias,
                        float* __restrict__ out, int N) {
  __shared__ float As[BK][BM + 4];
  __shared__ float Bs[BK][BN + 4];
  const int K = K1 + K2;
  const int tid = threadIdx.x;
  const int m0 = blockIdx.y * BM;
  const int n0 = blockIdx.x * BN;
  const int tx = tid & 15, ty = tid >> 4;
  const int lm = tid >> 2;        // 0..63
  const int lk = (tid & 3) * 4;   // 0,4,8,12
  float acc[4][4] = {};
  for (int k0 = 0; k0 < K; k0 += BK) {
    {  // A tile (activation, possibly split across two sources)
      const int m = m0 + lm;
      const int gk = k0 + lk;
      float4 av;
      if (gk + 3 < K1) {
        av = *(const float4*)(X1 + (size_t)m * K1 + gk);
      } else if (gk >= K1 && gk + 3 < K) {
        av = *(const float4*)(X2 + (size_t)m * K2 + (gk - K1));
      } else {
        float t[4];
#pragma unroll
        for (int j = 0; j < 4; ++j) {
          const int kk = gk + j;
          t[j] = (kk < K1) ? X1[(size_t)m * K1 + kk]
               : (kk < K)  ? X2[(size_t)m * K2 + (kk - K1)] : 0.f;
        }
        av = make_float4(t[0], t[1], t[2], t[3]);
      }
      As[lk + 0][lm] = av.x; As[lk + 1][lm] = av.y;
      As[lk + 2][lm] = av.z; As[lk + 3][lm] = av.w;
    }
    {  // W tile: Bs[k][n] = W[(n0+n)*K + k]
      const int n = n0 + lm;
      const int gk = k0 + lk;
      float4 wv;
      if (gk + 3 < K) {
        wv = *(const float4*)(W + (size_t)n * K + gk);
      } else {
        float t[4];
#pragma unroll
        for (int j = 0; j < 4; ++j) t[j] = (gk + j < K) ? W[(size_t)n * K + gk + j] : 0.f;
        wv = make_float4(t[0], t[1], t[2], t[3]);
      }
      Bs[lk + 0][lm] = wv.x; Bs[lk + 1][lm] = wv.y;
      Bs[lk + 2][lm] = wv.z; Bs[lk + 3][lm] = wv.w;
    }
    __syncthreads();
#pragma unroll
    for (int kk = 0; kk < BK; ++kk) {
      float a[4], b[4];
      *(float4*)a = *(const float4*)&As[kk][ty * 4];
      *(float4*)b = *(const float4*)&Bs[kk][tx * 4];
#pragma unroll
      for (int i = 0; i < 4; ++i)
#pragma unroll
        for (int j = 0; j < 4; ++j)
          acc[i][j] += a[i] * b[j];
    }
    __syncthreads();
  }
#pragma unroll
  for (int i = 0; i < 4; ++i) {
    const int m = m0 + ty * 4 + i;
#pragma unroll
    for (int j = 0; j < 4; ++j) {
      const int n = n0 + tx * 4 + j;
      const float v = acc[i][j] + bias[n];
      out[(size_t)m * N + n] = v > 0.f ? v : 0.f;
    }
  }
}

// out[m,n] (+= via split-K partial slices) = sum_k opA(A)[m,k] * B[k,n]; optional row scale 1/scale[m]
// TRANS_A: logical A[m,k] = A[k*lda + m], else A[m*lda + k]. B row-major [K][ldb].
template <bool TRANS_A, bool ROW_SCALE>
__global__ __launch_bounds__(256)
void gemm_plain_kernel(const float* __restrict__ A, int lda,
                       const float* __restrict__ B, int ldb,
                       float* __restrict__ out, int M, int N, int K,
                       int k_chunk, const float* __restrict__ scale) {
  __shared__ float As[BK][BM + 4];
  __shared__ float Bs[BK][BN + 4];
  const int tid = threadIdx.x;
  const int m0 = blockIdx.y * BM;
  const int n0 = blockIdx.x * BN;
  const int kb = blockIdx.z * k_chunk;
  const int ke = min(K, kb + k_chunk);
  const int tx = tid & 15, ty = tid >> 4;
  float acc[4][4] = {};
  for (int k0 = kb; k0 < ke; k0 += BK) {
    if (!TRANS_A) {
      const int lm = tid >> 2;
      const int lk = (tid & 3) * 4;
      const int gk = k0 + lk;
      float4 av = make_float4(0.f, 0.f, 0.f, 0.f);
      if (gk + 3 < ke) {
        av = *(const float4*)(A + (size_t)(m0 + lm) * lda + gk);
      } else {
        float t[4];
#pragma unroll
        for (int j = 0; j < 4; ++j)
          t[j] = (gk + j < ke) ? A[(size_t)(m0 + lm) * lda + gk + j] : 0.f;
        av = make_float4(t[0], t[1], t[2], t[3]);
      }
      As[lk + 0][lm] = av.x; As[lk + 1][lm] = av.y;
      As[lk + 2][lm] = av.z; As[lk + 3][lm] = av.w;
    } else {
      const int lk = tid >> 4;        // 0..15
      const int lm = (tid & 15) * 4;  // 0..60
      const int gk = k0 + lk;
      float4 av = make_float4(0.f, 0.f, 0.f, 0.f);
      if (gk < ke) av = *(const float4*)(A + (size_t)gk * lda + (m0 + lm));
      *(float4*)&As[lk][lm] = av;
    }
    {
      const int lk = tid >> 4;
      const int ln = (tid & 15) * 4;
      const int gk = k0 + lk;
      float4 bv = make_float4(0.f, 0.f, 0.f, 0.f);
      if (gk < ke) {
        if (n0 + ln + 3 < N) {
          bv = *(const float4*)(B + (size_t)gk * ldb + n0 + ln);
        } else {
          float t[4];
#pragma unroll
          for (int j = 0; j < 4; ++j)
            t[j] = (n0 + ln + j < N) ? B[(size_t)gk * ldb + n0 + ln + j] : 0.f;
          bv = make_float4(t[0], t[1], t[2], t[3]);
        }
      }
      *(float4*)&Bs[lk][ln] = bv;
    }
    __syncthreads();
#pragma unroll
    for (int kk = 0; kk < BK; ++kk) {
      float a[4], b[4];
      *(float4*)a = *(const float4*)&As[kk][ty * 4];
      *(float4*)b = *(const float4*)&Bs[kk][tx * 4];
#pragma unroll
      for (int i = 0; i < 4; ++i)
#pragma unroll
        for (int j = 0; j < 4; ++j)
          acc[i][j] += a[i] * b[j];
    }
    __syncthreads();
  }
  const size_t zoff = (size_t)blockIdx.z * M * N;
#pragma unroll
  for (int i = 0; i < 4; ++i) {
    const int m = m0 + ty * 4 + i;
    float sc = 1.f;
    if (ROW_SCALE) sc = 1.f / scale[m];
#pragma unroll
    for (int j = 0; j < 4; ++j) {
      const int n = n0 + tx * 4 + j;
      if (n < N) out[zoff + (size_t)m * N + n] = acc[i][j] * sc;
    }
  }
}

__global__ __launch_bounds__(256)
void rowsum_kernel(const float* __restrict__ A, float* __restrict__ out, int width) {
  __shared__ float red[256];
  const int row = blockIdx.x;
  const float* r = A + (size_t)row * width;
  float s = 0.f;
  for (int j = threadIdx.x; j < width; j += 256) s += r[j];
  red[threadIdx.x] = s;
  __syncthreads();
  for (int st = 128; st > 0; st >>= 1) {
    if (threadIdx.x < st) red[threadIdx.x] += red[threadIdx.x + st];
    __syncthreads();
  }
  if (threadIdx.x == 0) out[row] = red[0];
}

__global__ __launch_bounds__(256)
void colsum_stage1_kernel(const float* __restrict__ A, float* __restrict__ part, int M, int N) {
  const int col = blockIdx.x * 256 + threadIdx.x;
  const int rows = M / gridDim.y;
  const int r0 = blockIdx.y * rows;
  if (col < N) {
    float s = 0.f;
    for (int r = r0; r < r0 + rows; ++r) s += A[(size_t)r * N + col];
    part[(size_t)blockIdx.y * N + col] = s;
  }
}

__global__ __launch_bounds__(256)
void reduce_add_kernel(const float* __restrict__ part, float* __restrict__ out, int n, int S) {
  const int i = blockIdx.x * 256 + threadIdx.x;
  if (i < n) {
    float s = 0.f;
    for (int c = 0; c < S; ++c) s += part[(size_t)c * n + i];
    out[i] = s;
  }
}

template <bool RELU>
__global__ __launch_bounds__(64)
void matvec_kernel(const float* __restrict__ Wm, const float* __restrict__ bias,
                   const float* __restrict__ x, float* __restrict__ out, int K) {
  const int h = blockIdx.x;
  float s = 0.f;
  for (int k = threadIdx.x; k < K; k += 64) s += Wm[(size_t)h * K + k] * x[k];
#pragma unroll
  for (int off = 32; off > 0; off >>= 1) s += __shfl_down(s, off, 64);
  if (threadIdx.x == 0) {
    if (bias) s += bias[h];
    out[h] = RELU ? fmaxf(s, 0.f) : s;
  }
}

// out[j] = sum_k v[k] * Bm[k*N + j]
__global__ __launch_bounds__(256)
void vecmat_cols_kernel(const float* __restrict__ v, const float* __restrict__ Bm,
                        float* __restrict__ out, int K, int N) {
  const int j = blockIdx.x * 256 + threadIdx.x;
  if (j < N) {
    float s = 0.f;
    for (int k = 0; k < K; ++k) s += v[k] * Bm[(size_t)k * N + j];
    out[j] = s;
  }
}

__global__ __launch_bounds__(64)
void final3_kernel(const float* __restrict__ W3, const float* __restrict__ b3,
                   const float* __restrict__ z, float* __restrict__ y) {
  float s0 = 0.f, s1 = 0.f, s2 = 0.f;
  for (int k = threadIdx.x; k < H; k += 64) {
    const float zk = z[k];
    s0 += W3[k] * zk;
    s1 += W3[H + k] * zk;
    s2 += W3[2 * H + k] * zk;
  }
#pragma unroll
  for (int off = 32; off > 0; off >>= 1) {
    s0 += __shfl_down(s0, off, 64);
    s1 += __shfl_down(s1, off, 64);
    s2 += __shfl_down(s2, off, 64);
  }
  if (threadIdx.x == 0) {
    s0 += b3[0]; s1 += b3[1]; s2 += b3[2];
    const float m = fmaxf(s0, fmaxf(s1, s2));
    const float e0 = expf(s0 - m), e1 = expf(s1 - m), e2 = expf(s2 - m);
    const float d = e0 + e1 + e2;
    y[0] = e0 / d; y[1] = e1 / d; y[2] = e2 / d;
  }
}

}  // namespace

extern "C" void kernel_launch(void* const* d_in, const int* in_sizes, int n_in,
                              void* d_out, int out_size, void* d_ws, size_t ws_size,
                              hipStream_t stream) {
  const int* p_idx = (const int*)d_in[0];
  const int* h_idx = (const int*)d_in[1];
  const float* emb  = (const float*)d_in[2];
  const float* W_a1 = (const float*)d_in[3];
  const float* b_a1 = (const float*)d_in[4];
  const float* W_a2 = (const float*)d_in[5];
  const float* b_a2 = (const float*)d_in[6];
  const float* W_c1 = (const float*)d_in[7];
  const float* b_c1 = (const float*)d_in[8];
  const float* W_c2 = (const float*)d_in[9];
  const float* b_c2 = (const float*)d_in[10];
  const float* W_g1 = (const float*)d_in[11];
  const float* b_g1 = (const float*)d_in[12];
  const float* W_g2 = (const float*)d_in[13];
  const float* b_g2 = (const float*)d_in[14];
  const float* W_g3 = (const float*)d_in[15];
  const float* b_g3 = (const float*)d_in[16];

  float* ws  = (float*)d_ws;
  float* out = (float*)d_out;

  float* pe   = ws + WS_PEHE;              // [8192][300], rows 0..4095 = p, 4096.. = h
  float* he   = pe + (size_t)LP * D;
  float* t1   = ws + WS_T1;                // [8192][512]
  float* fpfh = ws + WS_FPFH;              // [8192][512]
  float* fp   = fpfh;                      // [4096][512]
  float* fh   = fpfh + (size_t)LP * H;     // [4096][512], also viewed as Bfh [512][4096]

  // 1. embedding gather (p and h fused)
  gather_kernel<<<LT, 128, 0, stream>>>(p_idx, h_idx, emb, pe);

  // 2. attend: relu(relu(x W_a1^T + b) W_a2^T + b), M = 8192 fused
  linear_relu_kernel<<<dim3(H / BN, LT / BM), 256, 0, stream>>>(pe, D, nullptr, 0, W_a1, b_a1, t1, H);
  linear_relu_kernel<<<dim3(H / BN, LT / BM), 256, 0, stream>>>(t1, H, nullptr, 0, W_a2, b_a2, fpfh, H);

  // 3. E = fp @ reshape(fh, [512, 4096])   (the only place E is touched)
  gemm_plain_kernel<false, false><<<dim3(LH / BN, LP / BM, 1), 256, 0, stream>>>(
      fp, H, fh, LH, out + OUT_E, LP, LH, H, H, nullptr);

  // 4. eik = fp @ rowsum(Bfh);  ekj = colsum(fp) @ Bfh   (factored — no E read-back)
  rowsum_kernel<<<H, 256, 0, stream>>>(fh, ws + WS_SH, LH);                     // s_h[k] = sum_j Bfh[k,j]
  matvec_kernel<false><<<LP, 64, 0, stream>>>(fp, nullptr, ws + WS_SH, ws + WS_EIK, H);
  colsum_stage1_kernel<<<dim3(H / 256, 16), 256, 0, stream>>>(fp, ws + WS_PART2, LP, H);
  reduce_add_kernel<<<H / 256, 256, 0, stream>>>(ws + WS_PART2, ws + WS_CF, H, 16);
  vecmat_cols_kernel<<<LH / 256, 256, 0, stream>>>(ws + WS_CF, fh, ws + WS_EKJ, H, LH);

  // 5. Gh = Bfh @ h_emb  [512 x 300], split-K=8
  gemm_plain_kernel<false, false><<<dim3(5, H / BM, 8), 256, 0, stream>>>(
      fh, LH, he, D, ws + WS_PART, H, D, LH, LH / 8, nullptr);
  reduce_add_kernel<<<(H * D + 255) / 256, 256, 0, stream>>>(ws + WS_PART, ws + WS_GH, H * D, 8);
  // 6. Gp = fp^T @ p_emb  [512 x 300], split-K=8
  gemm_plain_kernel<true, false><<<dim3(5, H / BM, 8), 256, 0, stream>>>(
      fp, H, pe, D, ws + WS_PART, H, D, LP, LP / 8, nullptr);
  reduce_add_kernel<<<(H * D + 255) / 256, 256, 0, stream>>>(ws + WS_PART, ws + WS_GP, H * D, 8);

  // 7. beta = diag(1/eik) fp @ Gh ;  alpha = diag(1/ekj) Bfh^T @ Gp
  gemm_plain_kernel<false, true><<<dim3(5, LP / BM, 1), 256, 0, stream>>>(
      fp, H, ws + WS_GH, D, out + OUT_BETA, LP, D, H, H, ws + WS_EIK);
  gemm_plain_kernel<true, true><<<dim3(5, LH / BM, 1), 256, 0, stream>>>(
      fh, LH, ws + WS_GP, D, out + OUT_ALPHA, LH, D, H, H, ws + WS_EKJ);

  // 8. comp: relu(relu(cat(emb, beta|alpha) W_c1^T + b) W_c2^T + b), M = 8192 fused
  //    (beta at out+OUT_BETA and alpha at out+OUT_ALPHA are contiguous => one [8192][300] tensor)
  linear_relu_kernel<<<dim3(H / BN, LT / BM), 256, 0, stream>>>(pe, D, out + OUT_BETA, D, W_c1, b_c1, t1, H);
  linear_relu_kernel<<<dim3(H / BN, LT / BM), 256, 0, stream>>>(t1, H, nullptr, 0, W_c2, b_c2, fpfh, H);

  // 9. v1 / v2 = column sums of comp output halves
  colsum_stage1_kernel<<<dim3(H / 256, 16), 256, 0, stream>>>(fpfh, ws + WS_PART2, LP, H);
  reduce_add_kernel<<<H / 256, 256, 0, stream>>>(ws + WS_PART2, out + OUT_V1, H, 16);
  colsum_stage1_kernel<<<dim3(H / 256, 16), 256, 0, stream>>>(fpfh + (size_t)LP * H, ws + WS_PART2, LH, H);
  reduce_add_kernel<<<H / 256, 256, 0, stream>>>(ws + WS_PART2, out + OUT_V2, H, 16);

  // 10. final MLP + softmax (v1||v2 is contiguous in d_out)
  matvec_kernel<true><<<H, 64, 0, stream>>>(W_g1, b_g1, out + OUT_V1, ws + WS_G1V, 2 * H);
  matvec_kernel<true><<<H, 64, 0, stream>>>(W_g2, b_g2, ws + WS_G1V, ws + WS_G2V, H);
  final3_kernel<<<1, 64, 0, stream>>>(W_g3, b_g3, ws + WS_G2V, out + OUT_Y);
}